// Round 1
// baseline (315.384 us; speedup 1.0000x reference)
//
#include <hip/hip_runtime.h>
#include <hip/hip_fp16.h>

typedef _Float16 half8_t __attribute__((ext_vector_type(8)));
typedef _Float16 half4_t __attribute__((ext_vector_type(4)));
typedef float f32x4 __attribute__((ext_vector_type(4)));

#define TILE 128
#define BK 32

__device__ __forceinline__ void gload_lds16(const void* g, void* l) {
    __builtin_amdgcn_global_load_lds(
        (const __attribute__((address_space(1))) void*)g,
        (__attribute__((address_space(3))) void*)l,
        16, 0, 0);
}

// ---------------- x fp32 -> fp16 ----------------
__global__ __launch_bounds__(256) void cvt_f32_f16_kernel(
    const float* __restrict__ x, _Float16* __restrict__ xh, int n) {
    int i = (blockIdx.x * 256 + threadIdx.x) * 4;
    if (i < n) {
        float4 v = *(const float4*)(x + i);
        half4_t h;
        h[0] = (_Float16)v.x; h[1] = (_Float16)v.y;
        h[2] = (_Float16)v.z; h[3] = (_Float16)v.w;
        *(half4_t*)(xh + i) = h;
    }
}

// ---------------- PQ quantize: weight -> wq (fp16) ----------------
// groups = (weight / row_scale).reshape(-1, 8); argmin over 256 codewords;
// wq = codebook[idx] * row_scale, stored fp16 [O][I].
__global__ __launch_bounds__(256) void pq_quant_kernel(
    const float* __restrict__ W, const float* __restrict__ cb,
    const float* __restrict__ rs, _Float16* __restrict__ wq,
    int groups_per_row, int n_groups) {
    __shared__ float scb[256 * 8];
    int tid = threadIdx.x;
    // stage codebook (8 KB) into LDS
    for (int i = tid; i < 256 * 8 / 4; i += 256)
        ((float4*)scb)[i] = ((const float4*)cb)[i];
    __syncthreads();

    const int GPT = 4;
    int gbase = blockIdx.x * (256 * GPT) + tid;
    for (int j = 0; j < GPT; j++) {
        int g = gbase + j * 256;
        if (g >= n_groups) continue;
        int o = g / groups_per_row;
        float rscale = rs[o];
        const float* wp = W + (size_t)g * 8;
        float4 w0 = *(const float4*)wp;
        float4 w1 = *(const float4*)(wp + 4);
        float gv[8];
        gv[0] = w0.x / rscale; gv[1] = w0.y / rscale;
        gv[2] = w0.z / rscale; gv[3] = w0.w / rscale;
        gv[4] = w1.x / rscale; gv[5] = w1.y / rscale;
        gv[6] = w1.z / rscale; gv[7] = w1.w / rscale;

        float best = 1e30f, second = 1e30f;
        int bidx = 0;
        for (int k = 0; k < 256; k++) {
            float4 c0 = *(const float4*)(scb + k * 8);
            float4 c1 = *(const float4*)(scb + k * 8 + 4);
            float d, acc;
            d = gv[0] - c0.x; acc = d * d;
            d = gv[1] - c0.y; acc = fmaf(d, d, acc);
            d = gv[2] - c0.z; acc = fmaf(d, d, acc);
            d = gv[3] - c0.w; acc = fmaf(d, d, acc);
            d = gv[4] - c1.x; acc = fmaf(d, d, acc);
            d = gv[5] - c1.y; acc = fmaf(d, d, acc);
            d = gv[6] - c1.z; acc = fmaf(d, d, acc);
            d = gv[7] - c1.w; acc = fmaf(d, d, acc);
            if (acc < best) { second = best; best = acc; bidx = k; }
            else if (acc < second) { second = acc; }
        }
        // near-tie: re-scan in fp64 so argmin matches the fp64 numpy reference
        if (second - best < 5e-4f) {
            double gd[8];
            double rsd = (double)rscale;
            for (int i = 0; i < 8; i++) gd[i] = (double)wp[i] / rsd;
            double bestd = 1e300;
            int bi = 0;
            for (int k = 0; k < 256; k++) {
                const float* c = scb + k * 8;
                double acc = 0.0;
                for (int i = 0; i < 8; i++) {
                    double d = gd[i] - (double)c[i];
                    acc = fma(d, d, acc);
                }
                if (acc < bestd) { bestd = acc; bi = k; }
            }
            bidx = bi;
        }
        const float* c = scb + bidx * 8;
        half8_t out;
        for (int i = 0; i < 8; i++) out[i] = (_Float16)(c[i] * rscale);
        *(half8_t*)(wq + (size_t)g * 8) = out;
    }
}

// ---------------- GEMM: C[M][N] = A[M][K] @ B[N][K]^T + bias ----------------
// fp16 MFMA 16x16x32, 128x128 block tile, 4 waves each 64x64, BK=32,
// global_load_lds width-16 staging (m97 structure).
__global__ __launch_bounds__(256) void gemm_f16_kernel(
    const _Float16* __restrict__ A, const _Float16* __restrict__ B,
    const float* __restrict__ bias, float* __restrict__ C,
    int M, int N, int K) {
    __shared__ _Float16 sA[TILE * BK];
    __shared__ _Float16 sB[TILE * BK];
    int tid = threadIdx.x;
    int wave = tid >> 6, lane = tid & 63;
    int wm = wave >> 1, wn = wave & 1;
    int bm = blockIdx.y * TILE, bn = blockIdx.x * TILE;

    f32x4 acc[4][4] = {};

    // staging constants: issue j covers rows [j*64 + wave*16, +16), lane l ->
    // row j*64+wave*16+(l>>2), k-chunk (l&3)*8 halves (16B per lane)
    int srow = wave * 16 + (lane >> 2);
    int skc = (lane & 3) * 8;

    const int kIters = K / BK;
    for (int kt = 0; kt < kIters; kt++) {
        int k0 = kt * BK;
        __syncthreads();
#pragma unroll
        for (int j = 0; j < 2; j++) {
            int row = j * 64 + srow;
            int ldsbase = (j * 64 + wave * 16) * BK;
            gload_lds16(A + (size_t)(bm + row) * K + k0 + skc, &sA[ldsbase]);
            gload_lds16(B + (size_t)(bn + row) * K + k0 + skc, &sB[ldsbase]);
        }
        __syncthreads();

        half8_t a[4], b[4];
#pragma unroll
        for (int mt = 0; mt < 4; mt++)
            a[mt] = *(const half8_t*)&sA[(wm * 64 + mt * 16 + (lane & 15)) * BK + (lane >> 4) * 8];
#pragma unroll
        for (int nt = 0; nt < 4; nt++)
            b[nt] = *(const half8_t*)&sB[(wn * 64 + nt * 16 + (lane & 15)) * BK + (lane >> 4) * 8];
#pragma unroll
        for (int mt = 0; mt < 4; mt++)
#pragma unroll
            for (int nt = 0; nt < 4; nt++)
                acc[mt][nt] = __builtin_amdgcn_mfma_f32_16x16x32_f16(
                    a[mt], b[nt], acc[mt][nt], 0, 0, 0);
    }

    // epilogue: D[row=(lane>>4)*4+r][col=lane&15] per 16x16 tile
    int col_base = bn + wn * 64;
    int row_base = bm + wm * 64;
#pragma unroll
    for (int nt = 0; nt < 4; nt++) {
        int col = col_base + nt * 16 + (lane & 15);
        float bv = bias[col];
#pragma unroll
        for (int mt = 0; mt < 4; mt++) {
            int r0 = row_base + mt * 16 + (lane >> 4) * 4;
#pragma unroll
            for (int r = 0; r < 4; r++)
                C[(size_t)(r0 + r) * N + col] = acc[mt][nt][r] + bv;
        }
    }
}

extern "C" void kernel_launch(void* const* d_in, const int* in_sizes, int n_in,
                              void* d_out, int out_size, void* d_ws, size_t ws_size,
                              hipStream_t stream) {
    const float* x        = (const float*)d_in[0];
    const float* weight   = (const float*)d_in[1];
    const float* codebook = (const float*)d_in[2];
    const float* rowscale = (const float*)d_in[3];
    const float* bias     = (const float*)d_in[4];
    float* out = (float*)d_out;

    int O = in_sizes[3];          // row_scale has O elements
    int I = in_sizes[1] / O;      // weight is O*I
    int M = in_sizes[0] / I;      // x is (B*S)*I
    const int D = 8;
    int n_groups = O * I / D;

    _Float16* xh = (_Float16*)d_ws;
    _Float16* wq = (_Float16*)((char*)d_ws + (size_t)M * I * sizeof(_Float16));

    int n_x = M * I;
    cvt_f32_f16_kernel<<<(n_x / 4 + 255) / 256, 256, 0, stream>>>(x, xh, n_x);
    pq_quant_kernel<<<(n_groups / 4 + 255) / 256, 256, 0, stream>>>(
        weight, codebook, rowscale, wq, I / D, n_groups);
    gemm_f16_kernel<<<dim3(O / TILE, M / TILE), 256, 0, stream>>>(
        xh, wq, bias, out, M, O, I);
}

// Round 2
// 243.389 us; speedup vs baseline: 1.2958x; 1.2958x over previous
//
#include <hip/hip_runtime.h>
#include <hip/hip_fp16.h>

typedef _Float16 half8_t __attribute__((ext_vector_type(8)));
typedef _Float16 half4_t __attribute__((ext_vector_type(4)));
typedef float f32x4 __attribute__((ext_vector_type(4)));

#define TILE 128
#define BK 32

__device__ __forceinline__ void gload_lds16(const void* g, void* l) {
    __builtin_amdgcn_global_load_lds(
        (const __attribute__((address_space(1))) void*)g,
        (__attribute__((address_space(3))) void*)l,
        16, 0, 0);
}

// ---------------- x fp32 -> fp16 ----------------
__global__ __launch_bounds__(256) void cvt_f32_f16_kernel(
    const float* __restrict__ x, _Float16* __restrict__ xh, int n) {
    int i = (blockIdx.x * 256 + threadIdx.x) * 4;
    if (i < n) {
        float4 v = *(const float4*)(x + i);
        half4_t h;
        h[0] = (_Float16)v.x; h[1] = (_Float16)v.y;
        h[2] = (_Float16)v.z; h[3] = (_Float16)v.w;
        *(half4_t*)(xh + i) = h;
    }
}

// ---------------- PQ quantize: weight -> wq (fp16) ----------------
// v2: codeword-outer loop, 4 groups/thread, codebook via scalar (constant
// cache) loads, score = |c|^2 - 2 g.c (gap-identical to |g-c|^2), med3 top-2
// tracking, fp64 near-tie rescan (unchanged semantics).
__global__ __launch_bounds__(256) void pq_quant_kernel(
    const float* __restrict__ W, const float* __restrict__ cb,
    const float* __restrict__ rs, _Float16* __restrict__ wq,
    int groups_per_row, int n_groups) {
    __shared__ float c2s[256];
    int tid = threadIdx.x;
    // precompute |c|^2 per codeword (one per thread; blockDim == 256 == K)
    {
        const float* cp = cb + tid * 8;
        float4 a = *(const float4*)cp;
        float4 b = *(const float4*)(cp + 4);
        float s = a.x * a.x;
        s = fmaf(a.y, a.y, s); s = fmaf(a.z, a.z, s); s = fmaf(a.w, a.w, s);
        s = fmaf(b.x, b.x, s); s = fmaf(b.y, b.y, s); s = fmaf(b.z, b.z, s);
        s = fmaf(b.w, b.w, s);
        c2s[tid] = s;
    }
    __syncthreads();

    const int NG = 4;
    int gbase = blockIdx.x * (256 * NG) + tid;

    float gv[NG][8];
    float rscale[NG];
#pragma unroll
    for (int j = 0; j < NG; j++) {
        int g = gbase + j * 256;
        if (g >= n_groups) g = n_groups - 1;       // clamp for load; store guarded
        int o = g / groups_per_row;
        float rsv = rs[o];
        rscale[j] = rsv;
        float rinv = 1.0f / rsv;
        const float* wp = W + (size_t)g * 8;
        float4 w0 = *(const float4*)wp;
        float4 w1 = *(const float4*)(wp + 4);
        gv[j][0] = w0.x * rinv; gv[j][1] = w0.y * rinv;
        gv[j][2] = w0.z * rinv; gv[j][3] = w0.w * rinv;
        gv[j][4] = w1.x * rinv; gv[j][5] = w1.y * rinv;
        gv[j][6] = w1.z * rinv; gv[j][7] = w1.w * rinv;
    }

    float best[NG], sec[NG];
    int bidx[NG];
#pragma unroll
    for (int j = 0; j < NG; j++) { best[j] = 1e30f; sec[j] = 1e30f; bidx[j] = 0; }

#pragma unroll 4
    for (int k = 0; k < 256; k++) {
        // loop-uniform address -> scalar loads via constant cache
        const float* cp = cb + k * 8;
        float c0 = cp[0], c1 = cp[1], c2v = cp[2], c3 = cp[3];
        float c4 = cp[4], c5 = cp[5], c6 = cp[6], c7 = cp[7];
        float cc = c2s[k];                          // uniform LDS broadcast
#pragma unroll
        for (int j = 0; j < NG; j++) {
            float dot = gv[j][0] * c0;
            dot = fmaf(gv[j][1], c1, dot);
            dot = fmaf(gv[j][2], c2v, dot);
            dot = fmaf(gv[j][3], c3, dot);
            dot = fmaf(gv[j][4], c4, dot);
            dot = fmaf(gv[j][5], c5, dot);
            dot = fmaf(gv[j][6], c6, dot);
            dot = fmaf(gv[j][7], c7, dot);
            float s = fmaf(dot, -2.0f, cc);         // |c|^2 - 2 g.c
            bool cond = s < best[j];
            sec[j] = __builtin_amdgcn_fmed3f(s, best[j], sec[j]);
            best[j] = fminf(best[j], s);
            bidx[j] = cond ? k : bidx[j];
        }
    }

#pragma unroll
    for (int j = 0; j < NG; j++) {
        int g = gbase + j * 256;
        if (g >= n_groups) continue;
        int bi = bidx[j];
        // near-tie: re-scan in fp64 so argmin matches the fp64 reference
        if (sec[j] - best[j] < 5e-4f) {
            const float* wp = W + (size_t)g * 8;
            double gd[8];
            double rsd = (double)rscale[j];
            for (int i = 0; i < 8; i++) gd[i] = (double)wp[i] / rsd;
            double bestd = 1e300;
            int bi2 = 0;
            for (int k = 0; k < 256; k++) {
                const float* c = cb + k * 8;
                double acc = 0.0;
                for (int i = 0; i < 8; i++) {
                    double d = gd[i] - (double)c[i];
                    acc = fma(d, d, acc);
                }
                if (acc < bestd) { bestd = acc; bi2 = k; }
            }
            bi = bi2;
        }
        const float* c = cb + bi * 8;
        float rsv = rscale[j];
        half8_t outv;
#pragma unroll
        for (int i = 0; i < 8; i++) outv[i] = (_Float16)(c[i] * rsv);
        *(half8_t*)(wq + (size_t)g * 8) = outv;
    }
}

// ---------------- GEMM: C[M][N] = A[M][K] @ B[N][K]^T + bias ----------------
// fp16 MFMA 16x16x32, 128x128 block tile, 4 waves each 64x64, BK=32,
// global_load_lds width-16 staging (m97 structure).
__global__ __launch_bounds__(256) void gemm_f16_kernel(
    const _Float16* __restrict__ A, const _Float16* __restrict__ B,
    const float* __restrict__ bias, float* __restrict__ C,
    int M, int N, int K) {
    __shared__ _Float16 sA[TILE * BK];
    __shared__ _Float16 sB[TILE * BK];
    int tid = threadIdx.x;
    int wave = tid >> 6, lane = tid & 63;
    int wm = wave >> 1, wn = wave & 1;
    int bm = blockIdx.y * TILE, bn = blockIdx.x * TILE;

    f32x4 acc[4][4] = {};

    int srow = wave * 16 + (lane >> 2);
    int skc = (lane & 3) * 8;

    const int kIters = K / BK;
    for (int kt = 0; kt < kIters; kt++) {
        int k0 = kt * BK;
        __syncthreads();
#pragma unroll
        for (int j = 0; j < 2; j++) {
            int row = j * 64 + srow;
            int ldsbase = (j * 64 + wave * 16) * BK;
            gload_lds16(A + (size_t)(bm + row) * K + k0 + skc, &sA[ldsbase]);
            gload_lds16(B + (size_t)(bn + row) * K + k0 + skc, &sB[ldsbase]);
        }
        __syncthreads();

        half8_t a[4], b[4];
#pragma unroll
        for (int mt = 0; mt < 4; mt++)
            a[mt] = *(const half8_t*)&sA[(wm * 64 + mt * 16 + (lane & 15)) * BK + (lane >> 4) * 8];
#pragma unroll
        for (int nt = 0; nt < 4; nt++)
            b[nt] = *(const half8_t*)&sB[(wn * 64 + nt * 16 + (lane & 15)) * BK + (lane >> 4) * 8];
#pragma unroll
        for (int mt = 0; mt < 4; mt++)
#pragma unroll
            for (int nt = 0; nt < 4; nt++)
                acc[mt][nt] = __builtin_amdgcn_mfma_f32_16x16x32_f16(
                    a[mt], b[nt], acc[mt][nt], 0, 0, 0);
    }

    int col_base = bn + wn * 64;
    int row_base = bm + wm * 64;
#pragma unroll
    for (int nt = 0; nt < 4; nt++) {
        int col = col_base + nt * 16 + (lane & 15);
        float bv = bias[col];
#pragma unroll
        for (int mt = 0; mt < 4; mt++) {
            int r0 = row_base + mt * 16 + (lane >> 4) * 4;
#pragma unroll
            for (int r = 0; r < 4; r++)
                C[(size_t)(r0 + r) * N + col] = acc[mt][nt][r] + bv;
        }
    }
}

extern "C" void kernel_launch(void* const* d_in, const int* in_sizes, int n_in,
                              void* d_out, int out_size, void* d_ws, size_t ws_size,
                              hipStream_t stream) {
    const float* x        = (const float*)d_in[0];
    const float* weight   = (const float*)d_in[1];
    const float* codebook = (const float*)d_in[2];
    const float* rowscale = (const float*)d_in[3];
    const float* bias     = (const float*)d_in[4];
    float* out = (float*)d_out;

    int O = in_sizes[3];          // row_scale has O elements
    int I = in_sizes[1] / O;      // weight is O*I
    int M = in_sizes[0] / I;      // x is (B*S)*I
    const int D = 8;
    int n_groups = O * I / D;

    _Float16* xh = (_Float16*)d_ws;
    _Float16* wq = (_Float16*)((char*)d_ws + (size_t)M * I * sizeof(_Float16));

    int n_x = M * I;
    cvt_f32_f16_kernel<<<(n_x / 4 + 255) / 256, 256, 0, stream>>>(x, xh, n_x);
    pq_quant_kernel<<<(n_groups + 1023) / 1024, 256, 0, stream>>>(
        weight, codebook, rowscale, wq, I / D, n_groups);
    gemm_f16_kernel<<<dim3(O / TILE, M / TILE), 256, 0, stream>>>(
        xh, wq, bias, out, M, O, I);
}